// Round 1
// baseline (65519.012 us; speedup 1.0000x reference)
//
#include <hip/hip_runtime.h>
#include <cmath>

#define DIM 768
#define DEPTH 8
#define HEADS 12
#define DH 64
#define DFF 2048
#define NTOK 16384   // B*T*S = 2*32*256
#define BB 2
#define TT 32
#define SS 256

__device__ __forceinline__ float sigmoidf_(float x) { return 1.0f / (1.0f + __expf(-x)); }
__device__ __forceinline__ float geluf_(float x) {
  return 0.5f * x * (1.0f + erff(x * 0.70710678118654752f));
}

// ---------------- RMSNorm: one block per row of 768 ----------------
__global__ __launch_bounds__(256) void rmsnorm_kernel(
    const float* __restrict__ x, const float* __restrict__ w,
    float* __restrict__ out)
{
  int row = blockIdx.x;
  int tid = threadIdx.x;
  const float* xr = x + (size_t)row * DIM;
  float v0 = xr[tid], v1 = xr[tid + 256], v2 = xr[tid + 512];
  float ss = v0 * v0 + v1 * v1 + v2 * v2;
  #pragma unroll
  for (int off = 32; off; off >>= 1) ss += __shfl_xor(ss, off);
  __shared__ float sred[4];
  if ((tid & 63) == 0) sred[tid >> 6] = ss;
  __syncthreads();
  float tot = sred[0] + sred[1] + sred[2] + sred[3];
  float r = rsqrtf(tot * (1.0f / DIM) + 1e-6f);
  float* orow = out + (size_t)row * DIM;
  orow[tid]       = v0 * r * w[tid];
  orow[tid + 256] = v1 * r * w[tid + 256];
  orow[tid + 512] = v2 * r * w[tid + 512];
}

// ---------------- fp32 GEMM 128x128x16, 8x8 per thread ----------------
// MODE 0: C = A@B + bias ; MODE 1: C += A@B + bias ; MODE 2: C = C * gelu(A@B + bias)
template<int MODE>
__global__ __launch_bounds__(256) void gemm_f32(
    const float* __restrict__ A, const float* __restrict__ B,
    float* __restrict__ C, const float* __restrict__ bias,
    int M, int N, int K, int ldb)
{
  __shared__ __align__(16) float As[16][132];
  __shared__ __align__(16) float Bs[16][132];
  const int tid = threadIdx.x;
  const int bm = blockIdx.y * 128;
  const int bn = blockIdx.x * 128;
  const int tx = tid & 15;
  const int ty = tid >> 4;
  float acc[8][8];
  #pragma unroll
  for (int i = 0; i < 8; ++i)
    #pragma unroll
    for (int j = 0; j < 8; ++j) acc[i][j] = 0.0f;

  for (int k0 = 0; k0 < K; k0 += 16) {
    #pragma unroll
    for (int e = tid; e < 512; e += 256) {
      int r = e >> 2; int kk = (e & 3) << 2;
      const float4 va = *(const float4*)(A + (size_t)(bm + r) * K + k0 + kk);
      As[kk + 0][r] = va.x; As[kk + 1][r] = va.y;
      As[kk + 2][r] = va.z; As[kk + 3][r] = va.w;
      int kb = e >> 5; int c = (e & 31) << 2;
      *(float4*)&Bs[kb][c] = *(const float4*)(B + (size_t)(k0 + kb) * ldb + bn + c);
    }
    __syncthreads();
    #pragma unroll
    for (int kk = 0; kk < 16; ++kk) {
      float a[8], b[8];
      *(float4*)&a[0] = *(const float4*)&As[kk][ty * 8];
      *(float4*)&a[4] = *(const float4*)&As[kk][ty * 8 + 4];
      *(float4*)&b[0] = *(const float4*)&Bs[kk][tx * 8];
      *(float4*)&b[4] = *(const float4*)&Bs[kk][tx * 8 + 4];
      #pragma unroll
      for (int i = 0; i < 8; ++i)
        #pragma unroll
        for (int j = 0; j < 8; ++j)
          acc[i][j] = fmaf(a[i], b[j], acc[i][j]);
    }
    __syncthreads();
  }
  float bv[8];
  #pragma unroll
  for (int j = 0; j < 8; ++j) bv[j] = bias ? bias[bn + tx * 8 + j] : 0.0f;
  #pragma unroll
  for (int i = 0; i < 8; ++i) {
    float* cp = C + (size_t)(bm + ty * 8 + i) * N + bn + tx * 8;
    float r[8];
    #pragma unroll
    for (int j = 0; j < 8; ++j) r[j] = acc[i][j] + bv[j];
    if (MODE == 0) {
      *(float4*)cp       = make_float4(r[0], r[1], r[2], r[3]);
      *(float4*)(cp + 4) = make_float4(r[4], r[5], r[6], r[7]);
    } else if (MODE == 1) {
      float4 c0 = *(const float4*)cp;
      float4 c1 = *(const float4*)(cp + 4);
      c0.x += r[0]; c0.y += r[1]; c0.z += r[2]; c0.w += r[3];
      c1.x += r[4]; c1.y += r[5]; c1.z += r[6]; c1.w += r[7];
      *(float4*)cp = c0; *(float4*)(cp + 4) = c1;
    } else {
      float4 c0 = *(const float4*)cp;
      float4 c1 = *(const float4*)(cp + 4);
      c0.x *= geluf_(r[0]); c0.y *= geluf_(r[1]); c0.z *= geluf_(r[2]); c0.w *= geluf_(r[3]);
      c1.x *= geluf_(r[4]); c1.y *= geluf_(r[5]); c1.z *= geluf_(r[6]); c1.w *= geluf_(r[7]);
      *(float4*)cp = c0; *(float4*)(cp + 4) = c1;
    }
  }
}

// ---------------- N=12 projection + sigmoid (mix / gates) ----------------
__global__ __launch_bounds__(256) void proj12_kernel(
    const float* __restrict__ A, const float* __restrict__ Bw,
    const float* __restrict__ bias, float* __restrict__ out)
{
  int row = blockIdx.x * 4 + (threadIdx.x >> 6);
  int lane = threadIdx.x & 63;
  const float* ar = A + (size_t)row * DIM;
  float acc[HEADS];
  #pragma unroll
  for (int j = 0; j < HEADS; ++j) acc[j] = 0.0f;
  for (int k2 = lane; k2 < DIM; k2 += 64) {
    float a = ar[k2];
    const float* bw = Bw + (size_t)k2 * HEADS;
    #pragma unroll
    for (int j = 0; j < HEADS; ++j) acc[j] = fmaf(a, bw[j], acc[j]);
  }
  #pragma unroll
  for (int j = 0; j < HEADS; ++j) {
    #pragma unroll
    for (int off = 32; off; off >>= 1) acc[j] += __shfl_xor(acc[j], off);
  }
  if (lane < HEADS) {
    float r = acc[lane] + (bias ? bias[lane] : 0.0f);
    out[(size_t)row * HEADS + lane] = sigmoidf_(r);
  }
}

// ---------------- qkv postprocess: v-lerp, k-norm+gamma, rotary ----------------
__global__ __launch_bounds__(64) void qkv_fix_kernel(
    float* __restrict__ q, float* __restrict__ k, float* __restrict__ v,
    const float* __restrict__ rv, const float* __restrict__ mix,
    const float* __restrict__ kgam, int is_time)
{
  int tok = blockIdx.x; int h = blockIdx.y; int d = threadIdx.x;
  size_t idx = (size_t)tok * DIM + h * DH + d;
  float kv = k[idx];
  float ss = kv * kv;
  #pragma unroll
  for (int off = 32; off; off >>= 1) ss += __shfl_xor(ss, off);
  float nrm = fmaxf(sqrtf(ss), 1e-12f);
  kv = kv / nrm * (kgam[h * DH + d] + 1.0f) * 8.0f;   // sqrt(DH)=8
  float mv = mix[(size_t)tok * HEADS + h];
  float vv = v[idx];
  v[idx] = vv + mv * (rv[idx] - vv);
  float qv = q[idx];
  if (is_time) {
    int t = (tok >> 8) & 31;          // token = (b*32+t)*256+s
    int j = d & 31;
    float ang = (float)t * __expf(-(float)j * (9.210340371976184f / 32.0f));
    float cs = cosf(ang), sn = sinf(ang);
    float qp = __shfl_xor(qv, 32);
    float kp = __shfl_xor(kv, 32);
    float sgn = (d < 32) ? -1.0f : 1.0f;
    qv = qv * cs + sgn * qp * sn;
    kv = kv * cs + sgn * kp * sn;
  }
  q[idx] = qv;
  k[idx] = kv;
}

// ---------------- attention: one block per (batch', head) ----------------
__global__ __launch_bounds__(256) void attn_kernel(
    const float* __restrict__ q, const float* __restrict__ k,
    const float* __restrict__ v, const float* __restrict__ gate,
    float* __restrict__ o, int n, int is_time)
{
  int bp = blockIdx.x; int h = blockIdx.y;
  int base, step;
  if (is_time) { base = (bp >> 8) * (TT * SS) + (bp & 255); step = SS; }
  else         { base = bp * SS; step = 1; }
  int tid = threadIdx.x;
  __shared__ float qv[DH];
  __shared__ float sc[256];
  __shared__ float red[256];

  for (int qi = 0; qi < n; ++qi) {
    int tq = base + qi * step;
    if (tid < DH) qv[tid] = q[(size_t)tq * DIM + h * DH + tid];
    __syncthreads();
    float s = -3.4e38f;
    if (tid < n) {
      int tk = base + tid * step;
      const float* kp = k + (size_t)tk * DIM + h * DH;
      float acc = 0.0f;
      #pragma unroll
      for (int d = 0; d < DH; d += 4) {
        float4 k4 = *(const float4*)(kp + d);
        acc += qv[d] * k4.x + qv[d + 1] * k4.y + qv[d + 2] * k4.z + qv[d + 3] * k4.w;
      }
      acc *= 0.125f;                       // DH^-0.5
      acc = tanhf(acc * 0.02f) * 50.0f;    // softclamp
      if (is_time && tid > qi) acc = -3.4e38f;  // causal
      s = acc;
    }
    red[tid] = s;
    __syncthreads();
    for (int off = 128; off > 0; off >>= 1) {
      if (tid < off) red[tid] = fmaxf(red[tid], red[tid + off]);
      __syncthreads();
    }
    float m = red[0];
    __syncthreads();
    float e = (tid < n) ? __expf(s - m) : 0.0f;
    sc[tid] = e;
    red[tid] = e;
    __syncthreads();
    for (int off = 128; off > 0; off >>= 1) {
      if (tid < off) red[tid] += red[tid + off];
      __syncthreads();
    }
    float inv = 1.0f / red[0];
    int d = tid & 63; int c = tid >> 6;
    int clen = (n + 3) >> 2;
    int j0 = c * clen; int j1 = min(n, j0 + clen);
    float acc = 0.0f;
    for (int j = j0; j < j1; ++j) {
      int tk = base + j * step;
      acc += sc[j] * v[(size_t)tk * DIM + h * DH + d];
    }
    __syncthreads();
    red[tid] = acc;
    __syncthreads();
    if (tid < 64) {
      float r = red[tid] + red[tid + 64] + red[tid + 128] + red[tid + 192];
      r *= inv;
      r *= gate[(size_t)tq * HEADS + h];
      o[(size_t)tq * DIM + h * DH + tid] = r;
    }
    __syncthreads();
  }
}

// ---------------- driver ----------------
extern "C" void kernel_launch(void* const* d_in, const int* in_sizes, int n_in,
                              void* d_out, int out_size, void* d_ws, size_t ws_size,
                              hipStream_t stream)
{
  const float* tokens = (const float*)d_in[0];
  const float* attn_norm_w = (const float*)d_in[1];
  const float* Wq   = (const float*)d_in[2];
  const float* Wk   = (const float*)d_in[3];
  const float* Wv   = (const float*)d_in[4];
  const float* Wo   = (const float*)d_in[5];
  const float* Wg   = (const float*)d_in[6];
  const float* Wmix = (const float*)d_in[7];
  const float* bmix = (const float*)d_in[8];
  const float* kgam = (const float*)d_in[9];
  const float* ffw  = (const float*)d_in[10];
  const float* Win  = (const float*)d_in[11];
  const float* bin  = (const float*)d_in[12];
  const float* Wout = (const float*)d_in[13];
  const float* bout = (const float*)d_in[14];
  const float* vrw  = (const float*)d_in[15];
  const float* vrW  = (const float*)d_in[16];
  const float* fnw  = (const float*)d_in[17];

  const size_t NT = (size_t)NTOK * DIM;   // 12,582,912 floats
  float* ws  = (float*)d_ws;
  float* x   = ws;
  float* tn  = x  + NT;
  float* q   = tn + NT;
  float* k   = q  + NT;
  float* v   = k  + NT;
  float* rv  = v  + NT;
  float* mix = rv + NT;
  float* gate = mix + (size_t)NTOK * HEADS;
  float* hg  = q;   // aliases q..v region (needs 33.5M floats < 37.7M available)

  hipMemcpyAsync(x, tokens, NT * sizeof(float), hipMemcpyDeviceToDevice, stream);

  // value residual: rv = rmsnorm(tokens, vrw) @ vrW
  rmsnorm_kernel<<<NTOK, 256, 0, stream>>>(tokens, vrw, tn);
  gemm_f32<0><<<dim3(DIM / 128, NTOK / 128), 256, 0, stream>>>(
      tn, vrW, rv, nullptr, NTOK, DIM, DIM, DIM);

  for (int i = 0; i < DEPTH; ++i) {
    int is_time = ((i + 1) % 4 == 0) ? 1 : 0;
    rmsnorm_kernel<<<NTOK, 256, 0, stream>>>(x, attn_norm_w + (size_t)i * DIM, tn);
    gemm_f32<0><<<dim3(6, 128), 256, 0, stream>>>(
        tn, Wq + (size_t)i * DIM * DIM, q, nullptr, NTOK, DIM, DIM, DIM);
    gemm_f32<0><<<dim3(6, 128), 256, 0, stream>>>(
        tn, Wk + (size_t)i * DIM * DIM, k, nullptr, NTOK, DIM, DIM, DIM);
    gemm_f32<0><<<dim3(6, 128), 256, 0, stream>>>(
        tn, Wv + (size_t)i * DIM * DIM, v, nullptr, NTOK, DIM, DIM, DIM);
    proj12_kernel<<<NTOK / 4, 256, 0, stream>>>(
        tn, Wmix + (size_t)i * DIM * HEADS, bmix + (size_t)i * HEADS, mix);
    proj12_kernel<<<NTOK / 4, 256, 0, stream>>>(
        tn, Wg + (size_t)i * DIM * HEADS, nullptr, gate);
    qkv_fix_kernel<<<dim3(NTOK, HEADS), 64, 0, stream>>>(
        q, k, v, rv, mix, kgam + (size_t)i * HEADS * DH, is_time);
    if (is_time)
      attn_kernel<<<dim3(BB * SS, HEADS), 256, 0, stream>>>(q, k, v, gate, tn, TT, 1);
    else
      attn_kernel<<<dim3(BB * TT, HEADS), 256, 0, stream>>>(q, k, v, gate, tn, SS, 0);
    gemm_f32<1><<<dim3(6, 128), 256, 0, stream>>>(
        tn, Wo + (size_t)i * DIM * DIM, x, nullptr, NTOK, DIM, DIM, DIM);
    // FF
    rmsnorm_kernel<<<NTOK, 256, 0, stream>>>(x, ffw + (size_t)i * DIM, tn);
    gemm_f32<0><<<dim3(16, 128), 256, 0, stream>>>(
        tn, Win + (size_t)i * DIM * 2 * DFF, hg, bin + (size_t)i * 2 * DFF,
        NTOK, DFF, DIM, 2 * DFF);
    gemm_f32<2><<<dim3(16, 128), 256, 0, stream>>>(
        tn, Win + (size_t)i * DIM * 2 * DFF + DFF, hg, bin + (size_t)i * 2 * DFF + DFF,
        NTOK, DFF, DIM, 2 * DFF);
    gemm_f32<1><<<dim3(6, 128), 256, 0, stream>>>(
        hg, Wout + (size_t)i * DFF * DIM, x, bout + (size_t)i * DIM,
        NTOK, DIM, DFF, DIM);
  }
  rmsnorm_kernel<<<NTOK, 256, 0, stream>>>(x, fnw, (float*)d_out);
}

// Round 2
// 26188.602 us; speedup vs baseline: 2.5018x; 2.5018x over previous
//
#include <hip/hip_runtime.h>
#include <cmath>

#define DIM 768
#define DEPTH 8
#define HEADS 12
#define DH 64
#define DFF 2048
#define NTOK 16384   // B*T*S = 2*32*256
#define BB 2
#define TT 32
#define SS 256

__device__ __forceinline__ float sigmoidf_(float x) { return 1.0f / (1.0f + __expf(-x)); }
__device__ __forceinline__ float geluf_(float x) {
  return 0.5f * x * (1.0f + erff(x * 0.70710678118654752f));
}

// ---------------- RMSNorm: one block per row of 768 ----------------
__global__ __launch_bounds__(256) void rmsnorm_kernel(
    const float* __restrict__ x, const float* __restrict__ w,
    float* __restrict__ out)
{
  int row = blockIdx.x;
  int tid = threadIdx.x;
  const float* xr = x + (size_t)row * DIM;
  float v0 = xr[tid], v1 = xr[tid + 256], v2 = xr[tid + 512];
  float ss = v0 * v0 + v1 * v1 + v2 * v2;
  #pragma unroll
  for (int off = 32; off; off >>= 1) ss += __shfl_xor(ss, off);
  __shared__ float sred[4];
  if ((tid & 63) == 0) sred[tid >> 6] = ss;
  __syncthreads();
  float tot = sred[0] + sred[1] + sred[2] + sred[3];
  float r = rsqrtf(tot * (1.0f / DIM) + 1e-6f);
  float* orow = out + (size_t)row * DIM;
  orow[tid]       = v0 * r * w[tid];
  orow[tid + 256] = v1 * r * w[tid + 256];
  orow[tid + 512] = v2 * r * w[tid + 512];
}

// ---------------- fp32 GEMM 128x128x16, 8x8 per thread ----------------
// MODE 0: C = A@B + bias ; MODE 1: C += A@B + bias ; MODE 2: C = C * gelu(A@B + bias)
template<int MODE>
__global__ __launch_bounds__(256) void gemm_f32(
    const float* __restrict__ A, const float* __restrict__ B,
    float* __restrict__ C, const float* __restrict__ bias,
    int M, int N, int K, int ldb)
{
  __shared__ __align__(16) float As[16][132];
  __shared__ __align__(16) float Bs[16][132];
  const int tid = threadIdx.x;
  const int bm = blockIdx.y * 128;
  const int bn = blockIdx.x * 128;
  const int tx = tid & 15;
  const int ty = tid >> 4;
  float acc[8][8];
  #pragma unroll
  for (int i = 0; i < 8; ++i)
    #pragma unroll
    for (int j = 0; j < 8; ++j) acc[i][j] = 0.0f;

  for (int k0 = 0; k0 < K; k0 += 16) {
    #pragma unroll
    for (int e = tid; e < 512; e += 256) {
      int r = e >> 2; int kk = (e & 3) << 2;
      const float4 va = *(const float4*)(A + (size_t)(bm + r) * K + k0 + kk);
      As[kk + 0][r] = va.x; As[kk + 1][r] = va.y;
      As[kk + 2][r] = va.z; As[kk + 3][r] = va.w;
      int kb = e >> 5; int c = (e & 31) << 2;
      *(float4*)&Bs[kb][c] = *(const float4*)(B + (size_t)(k0 + kb) * ldb + bn + c);
    }
    __syncthreads();
    #pragma unroll
    for (int kk = 0; kk < 16; ++kk) {
      float a[8], b[8];
      *(float4*)&a[0] = *(const float4*)&As[kk][ty * 8];
      *(float4*)&a[4] = *(const float4*)&As[kk][ty * 8 + 4];
      *(float4*)&b[0] = *(const float4*)&Bs[kk][tx * 8];
      *(float4*)&b[4] = *(const float4*)&Bs[kk][tx * 8 + 4];
      #pragma unroll
      for (int i = 0; i < 8; ++i)
        #pragma unroll
        for (int j = 0; j < 8; ++j)
          acc[i][j] = fmaf(a[i], b[j], acc[i][j]);
    }
    __syncthreads();
  }
  float bv[8];
  #pragma unroll
  for (int j = 0; j < 8; ++j) bv[j] = bias ? bias[bn + tx * 8 + j] : 0.0f;
  #pragma unroll
  for (int i = 0; i < 8; ++i) {
    float* cp = C + (size_t)(bm + ty * 8 + i) * N + bn + tx * 8;
    float r[8];
    #pragma unroll
    for (int j = 0; j < 8; ++j) r[j] = acc[i][j] + bv[j];
    if (MODE == 0) {
      *(float4*)cp       = make_float4(r[0], r[1], r[2], r[3]);
      *(float4*)(cp + 4) = make_float4(r[4], r[5], r[6], r[7]);
    } else if (MODE == 1) {
      float4 c0 = *(const float4*)cp;
      float4 c1 = *(const float4*)(cp + 4);
      c0.x += r[0]; c0.y += r[1]; c0.z += r[2]; c0.w += r[3];
      c1.x += r[4]; c1.y += r[5]; c1.z += r[6]; c1.w += r[7];
      *(float4*)cp = c0; *(float4*)(cp + 4) = c1;
    } else {
      float4 c0 = *(const float4*)cp;
      float4 c1 = *(const float4*)(cp + 4);
      c0.x *= geluf_(r[0]); c0.y *= geluf_(r[1]); c0.z *= geluf_(r[2]); c0.w *= geluf_(r[3]);
      c1.x *= geluf_(r[4]); c1.y *= geluf_(r[5]); c1.z *= geluf_(r[6]); c1.w *= geluf_(r[7]);
      *(float4*)cp = c0; *(float4*)(cp + 4) = c1;
    }
  }
}

// ---------------- N=12 projection + sigmoid (mix / gates) ----------------
__global__ __launch_bounds__(256) void proj12_kernel(
    const float* __restrict__ A, const float* __restrict__ Bw,
    const float* __restrict__ bias, float* __restrict__ out)
{
  int row = blockIdx.x * 4 + (threadIdx.x >> 6);
  int lane = threadIdx.x & 63;
  const float* ar = A + (size_t)row * DIM;
  float acc[HEADS];
  #pragma unroll
  for (int j = 0; j < HEADS; ++j) acc[j] = 0.0f;
  for (int k2 = lane; k2 < DIM; k2 += 64) {
    float a = ar[k2];
    const float* bw = Bw + (size_t)k2 * HEADS;
    #pragma unroll
    for (int j = 0; j < HEADS; ++j) acc[j] = fmaf(a, bw[j], acc[j]);
  }
  #pragma unroll
  for (int j = 0; j < HEADS; ++j) {
    #pragma unroll
    for (int off = 32; off; off >>= 1) acc[j] += __shfl_xor(acc[j], off);
  }
  if (lane < HEADS) {
    float r = acc[lane] + (bias ? bias[lane] : 0.0f);
    out[(size_t)row * HEADS + lane] = sigmoidf_(r);
  }
}

// ---------------- qkv postprocess: v-lerp, k-norm+gamma, rotary ----------------
__global__ __launch_bounds__(64) void qkv_fix_kernel(
    float* __restrict__ q, float* __restrict__ k, float* __restrict__ v,
    const float* __restrict__ rv, const float* __restrict__ mix,
    const float* __restrict__ kgam, int is_time)
{
  int tok = blockIdx.x; int h = blockIdx.y; int d = threadIdx.x;
  size_t idx = (size_t)tok * DIM + h * DH + d;
  float kv = k[idx];
  float ss = kv * kv;
  #pragma unroll
  for (int off = 32; off; off >>= 1) ss += __shfl_xor(ss, off);
  float nrm = fmaxf(sqrtf(ss), 1e-12f);
  kv = kv / nrm * (kgam[h * DH + d] + 1.0f) * 8.0f;   // sqrt(DH)=8
  float mv = mix[(size_t)tok * HEADS + h];
  float vv = v[idx];
  v[idx] = vv + mv * (rv[idx] - vv);
  float qv = q[idx];
  if (is_time) {
    int t = (tok >> 8) & 31;          // token = (b*32+t)*256+s
    int j = d & 31;
    float ang = (float)t * __expf(-(float)j * (9.210340371976184f / 32.0f));
    float cs = cosf(ang), sn = sinf(ang);
    float qp = __shfl_xor(qv, 32);
    float kp = __shfl_xor(kv, 32);
    float sgn = (d < 32) ? -1.0f : 1.0f;
    qv = qv * cs + sgn * qp * sn;
    kv = kv * cs + sgn * kp * sn;
  }
  q[idx] = qv;
  k[idx] = kv;
}

// ---------------- attention v2: data-parallel over queries ----------------
// One block per (G seqs, head); 256 threads, 1 query per thread.
// K/V staged once into LDS in chunks of 128 rows (2 x 32 KB).
// Softmax uses fixed max = 0: softclamp bounds |s|<=50 so e^s in
// [2e-22, 5e21] and sum <= 256*e^50 = 1.3e24 -- safely inside fp32.
// Inner-loop LDS reads are wave-broadcast (1-2 distinct addrs = free).
#define ACHUNK 128
__global__ __launch_bounds__(256) void attn_kernel(
    const float* __restrict__ q, const float* __restrict__ k,
    const float* __restrict__ v, const float* __restrict__ gate,
    float* __restrict__ o, int n, int ln, int is_time)
{
  __shared__ __align__(16) float Ks[ACHUNK][DH];
  __shared__ __align__(16) float Vs[ACHUNK][DH];
  const int tid = threadIdx.x;
  const int h = blockIdx.y;
  const int G = 256 >> ln;              // groups (sequences) per block
  const int g = tid >> ln;              // my group
  const int qi = tid & (n - 1);         // my query within group
  const int bp0 = blockIdx.x * G;
  const int step = is_time ? SS : 1;

  int bp = bp0 + g;
  int base = is_time ? ((bp >> 8) * (TT * SS) + (bp & 255)) : bp * SS;
  int tq = base + qi * step;

  float4 q4[16];
  const float4* qp = (const float4*)(q + (size_t)tq * DIM + h * DH);
  #pragma unroll
  for (int c = 0; c < 16; ++c) q4[c] = qp[c];

  float4 o4[16];
  #pragma unroll
  for (int c = 0; c < 16; ++c) o4[c] = make_float4(0.f, 0.f, 0.f, 0.f);
  float sum = 0.0f;

  for (int r0 = 0; r0 < 256; r0 += ACHUNK) {
    // cooperative load of rows [r0, r0+ACHUNK): 2048 float4s, 8 per thread
    #pragma unroll
    for (int w = 0; w < ACHUNK * (DH / 4) / 256; ++w) {
      int f = tid + w * 256;
      int r = f >> 4;                   // local row 0..127
      int c4 = f & 15;
      int rr = r0 + r;                  // global row 0..255
      int gg = rr >> ln;
      int jj = rr & (n - 1);
      int bpr = bp0 + gg;
      int baser = is_time ? ((bpr >> 8) * (TT * SS) + (bpr & 255)) : bpr * SS;
      int tok = baser + jj * step;
      size_t off = (size_t)tok * DIM + h * DH;
      *(float4*)&Ks[r][c4 * 4] = ((const float4*)(k + off))[c4];
      *(float4*)&Vs[r][c4 * 4] = ((const float4*)(v + off))[c4];
    }
    __syncthreads();

    int lo = max(r0, g * n);
    int hi = min(r0 + ACHUNK, (g + 1) * n);
    for (int r = lo; r < hi; ++r) {
      int j = r - g * n;                // key index within my sequence
      if (is_time && j > qi) break;     // causal
      int lr = r - r0;
      const float4* kr = (const float4*)&Ks[lr][0];
      float s = 0.0f;
      #pragma unroll
      for (int c = 0; c < 16; ++c) {
        float4 kk = kr[c];
        s += q4[c].x * kk.x + q4[c].y * kk.y + q4[c].z * kk.z + q4[c].w * kk.w;
      }
      s *= 0.125f;                      // DH^-0.5
      s = tanhf(s * 0.02f) * 50.0f;     // softclamp
      float p = __expf(s);
      sum += p;
      const float4* vr = (const float4*)&Vs[lr][0];
      #pragma unroll
      for (int c = 0; c < 16; ++c) {
        float4 vv = vr[c];
        o4[c].x += p * vv.x; o4[c].y += p * vv.y;
        o4[c].z += p * vv.z; o4[c].w += p * vv.w;
      }
    }
    __syncthreads();
  }

  float gt = gate[(size_t)tq * HEADS + h] / sum;
  float4* op = (float4*)(o + (size_t)tq * DIM + h * DH);
  #pragma unroll
  for (int c = 0; c < 16; ++c) {
    op[c] = make_float4(o4[c].x * gt, o4[c].y * gt, o4[c].z * gt, o4[c].w * gt);
  }
}

// ---------------- driver ----------------
extern "C" void kernel_launch(void* const* d_in, const int* in_sizes, int n_in,
                              void* d_out, int out_size, void* d_ws, size_t ws_size,
                              hipStream_t stream)
{
  const float* tokens = (const float*)d_in[0];
  const float* attn_norm_w = (const float*)d_in[1];
  const float* Wq   = (const float*)d_in[2];
  const float* Wk   = (const float*)d_in[3];
  const float* Wv   = (const float*)d_in[4];
  const float* Wo   = (const float*)d_in[5];
  const float* Wg   = (const float*)d_in[6];
  const float* Wmix = (const float*)d_in[7];
  const float* bmix = (const float*)d_in[8];
  const float* kgam = (const float*)d_in[9];
  const float* ffw  = (const float*)d_in[10];
  const float* Win  = (const float*)d_in[11];
  const float* bin  = (const float*)d_in[12];
  const float* Wout = (const float*)d_in[13];
  const float* bout = (const float*)d_in[14];
  const float* vrw  = (const float*)d_in[15];
  const float* vrW  = (const float*)d_in[16];
  const float* fnw  = (const float*)d_in[17];

  const size_t NT = (size_t)NTOK * DIM;   // 12,582,912 floats
  float* ws  = (float*)d_ws;
  float* x   = ws;
  float* tn  = x  + NT;
  float* q   = tn + NT;
  float* k   = q  + NT;
  float* v   = k  + NT;
  float* rv  = v  + NT;
  float* mix = rv + NT;
  float* gate = mix + (size_t)NTOK * HEADS;
  float* hg  = q;   // aliases q..v region (needs 33.5M floats < 37.7M available)

  hipMemcpyAsync(x, tokens, NT * sizeof(float), hipMemcpyDeviceToDevice, stream);

  // value residual: rv = rmsnorm(tokens, vrw) @ vrW
  rmsnorm_kernel<<<NTOK, 256, 0, stream>>>(tokens, vrw, tn);
  gemm_f32<0><<<dim3(DIM / 128, NTOK / 128), 256, 0, stream>>>(
      tn, vrW, rv, nullptr, NTOK, DIM, DIM, DIM);

  for (int i = 0; i < DEPTH; ++i) {
    int is_time = ((i + 1) % 4 == 0) ? 1 : 0;
    rmsnorm_kernel<<<NTOK, 256, 0, stream>>>(x, attn_norm_w + (size_t)i * DIM, tn);
    gemm_f32<0><<<dim3(6, 128), 256, 0, stream>>>(
        tn, Wq + (size_t)i * DIM * DIM, q, nullptr, NTOK, DIM, DIM, DIM);
    gemm_f32<0><<<dim3(6, 128), 256, 0, stream>>>(
        tn, Wk + (size_t)i * DIM * DIM, k, nullptr, NTOK, DIM, DIM, DIM);
    gemm_f32<0><<<dim3(6, 128), 256, 0, stream>>>(
        tn, Wv + (size_t)i * DIM * DIM, v, nullptr, NTOK, DIM, DIM, DIM);
    proj12_kernel<<<NTOK / 4, 256, 0, stream>>>(
        tn, Wmix + (size_t)i * DIM * HEADS, bmix + (size_t)i * HEADS, mix);
    proj12_kernel<<<NTOK / 4, 256, 0, stream>>>(
        tn, Wg + (size_t)i * DIM * HEADS, nullptr, gate);
    qkv_fix_kernel<<<dim3(NTOK, HEADS), 64, 0, stream>>>(
        q, k, v, rv, mix, kgam + (size_t)i * HEADS * DH, is_time);
    if (is_time) {
      // 512 sequences of n=32: G=8 seqs/block -> grid (64, 12)
      attn_kernel<<<dim3((BB * SS) / 8, HEADS), 256, 0, stream>>>(
          q, k, v, gate, tn, TT, 5, 1);
    } else {
      // 64 sequences of n=256: G=1 -> grid (64, 12)
      attn_kernel<<<dim3(BB * TT, HEADS), 256, 0, stream>>>(
          q, k, v, gate, tn, SS, 8, 0);
    }
    gemm_f32<1><<<dim3(6, 128), 256, 0, stream>>>(
        tn, Wo + (size_t)i * DIM * DIM, x, nullptr, NTOK, DIM, DIM, DIM);
    // FF
    rmsnorm_kernel<<<NTOK, 256, 0, stream>>>(x, ffw + (size_t)i * DIM, tn);
    gemm_f32<0><<<dim3(16, 128), 256, 0, stream>>>(
        tn, Win + (size_t)i * DIM * 2 * DFF, hg, bin + (size_t)i * 2 * DFF,
        NTOK, DFF, DIM, 2 * DFF);
    gemm_f32<2><<<dim3(16, 128), 256, 0, stream>>>(
        tn, Win + (size_t)i * DIM * 2 * DFF + DFF, hg, bin + (size_t)i * 2 * DFF + DFF,
        NTOK, DFF, DIM, 2 * DFF);
    gemm_f32<1><<<dim3(6, 128), 256, 0, stream>>>(
        hg, Wout + (size_t)i * DFF * DIM, x, bout + (size_t)i * DIM,
        NTOK, DIM, DFF, DIM);
  }
  rmsnorm_kernel<<<NTOK, 256, 0, stream>>>(x, fnw, (float*)d_out);
}

// Round 3
// 7402.985 us; speedup vs baseline: 8.8504x; 3.5376x over previous
//
#include <hip/hip_runtime.h>
#include <cmath>

#define DIM 768
#define DEPTH 8
#define HEADS 12
#define DH 64
#define DFF 2048
#define NTOK 16384   // B*T*S = 2*32*256
#define BB 2
#define TT 32
#define SS 256

typedef __attribute__((ext_vector_type(8))) short short8;
typedef __attribute__((ext_vector_type(4))) float f32x4;

__device__ __forceinline__ float sigmoidf_(float x) { return 1.0f / (1.0f + __expf(-x)); }
__device__ __forceinline__ float geluf_(float x) {
  return 0.5f * x * (1.0f + erff(x * 0.70710678118654752f));
}
__device__ __forceinline__ unsigned short f2bf(float x) {
  union { float f; unsigned int u; } a; a.f = x;
  unsigned int r = a.u + 0x7fff + ((a.u >> 16) & 1);   // RNE
  return (unsigned short)(r >> 16);
}
__device__ __forceinline__ float bf2f(unsigned short h) {
  union { unsigned int u; float f; } a; a.u = ((unsigned int)h) << 16;
  return a.f;
}
__device__ __forceinline__ void load_lds16(const void* g, void* l) {
  __builtin_amdgcn_global_load_lds(
      (const __attribute__((address_space(1))) unsigned int*)g,
      (__attribute__((address_space(3))) unsigned int*)l, 16, 0, 0);
}

// ---------------- RMSNorm: one block per row of 768 ----------------
template<int BF>
__global__ __launch_bounds__(256) void rmsnorm_kernel(
    const float* __restrict__ x, const float* __restrict__ w, void* __restrict__ outp)
{
  int row = blockIdx.x;
  int tid = threadIdx.x;
  const float* xr = x + (size_t)row * DIM;
  float v0 = xr[tid], v1 = xr[tid + 256], v2 = xr[tid + 512];
  float ss = v0 * v0 + v1 * v1 + v2 * v2;
  #pragma unroll
  for (int off = 32; off; off >>= 1) ss += __shfl_xor(ss, off);
  __shared__ float sred[4];
  if ((tid & 63) == 0) sred[tid >> 6] = ss;
  __syncthreads();
  float tot = sred[0] + sred[1] + sred[2] + sred[3];
  float r = rsqrtf(tot * (1.0f / DIM) + 1e-6f);
  if (BF) {
    unsigned short* orow = (unsigned short*)outp + (size_t)row * DIM;
    orow[tid]       = f2bf(v0 * r * w[tid]);
    orow[tid + 256] = f2bf(v1 * r * w[tid + 256]);
    orow[tid + 512] = f2bf(v2 * r * w[tid + 512]);
  } else {
    float* orow = (float*)outp + (size_t)row * DIM;
    orow[tid]       = v0 * r * w[tid];
    orow[tid + 256] = v1 * r * w[tid + 256];
    orow[tid + 512] = v2 * r * w[tid + 512];
  }
}

// ---------------- weight convert+transpose: W[K][N] f32 -> WT[N][K] bf16 ----------------
__global__ __launch_bounds__(256) void w_to_bt(
    const float* __restrict__ W, unsigned short* __restrict__ WT, int K, int N)
{
  __shared__ float t[32][33];
  int n0 = blockIdx.x * 32, k0 = blockIdx.y * 32;
  int c = threadIdx.x & 31, r8 = threadIdx.x >> 5;
  #pragma unroll
  for (int rr = r8; rr < 32; rr += 8)
    t[rr][c] = W[(size_t)(k0 + rr) * N + n0 + c];
  __syncthreads();
  #pragma unroll
  for (int rn = r8; rn < 32; rn += 8)
    WT[(size_t)(n0 + rn) * K + k0 + c] = f2bf(t[c][rn]);
}

// ---------------- bf16 MFMA GEMM: 128x128 tile, BK=32 (m97 structure) ----------------
// A: MxK bf16 row-major. BT: NxK bf16 row-major (= B transposed).
// MODE 0: Cf = A@B (+bias)            (fp32 out)
// MODE 1: Cf += A@B (+bias)           (fp32 accumulate)
// MODE 2: Hg = bf16(A@B + bias)       (bf16 out)
// MODE 3: Hg = bf16(Hg * gelu(A@B + bias))
template<int MODE>
__global__ __launch_bounds__(256) void gemm_bf16(
    const unsigned short* __restrict__ A, const unsigned short* __restrict__ BT,
    float* __restrict__ Cf, unsigned short* __restrict__ Hg,
    const float* __restrict__ bias, int M, int N, int K)
{
  __shared__ unsigned short As[128 * 32];
  __shared__ unsigned short Bs[128 * 32];
  const int tid = threadIdx.x;
  const int wave = tid >> 6;
  const int lane = tid & 63;
  const int bm = blockIdx.y * 128;
  const int bn = blockIdx.x * 128;
  const int wm = (wave & 1) * 64;
  const int wn = (wave >> 1) * 64;

  f32x4 acc[4][4];
  #pragma unroll
  for (int i = 0; i < 4; ++i)
    #pragma unroll
    for (int j = 0; j < 4; ++j) acc[i][j] = (f32x4){0.f, 0.f, 0.f, 0.f};

  // staging: wave w loads rows [32w, 32w+32) of each tile, 2 insts x 16 rows
  const int srow = wave * 32 + (lane >> 2);
  const int skoff = (lane & 3) * 8;            // ushorts (16 B)
  const unsigned short* gA = A + (size_t)(bm + srow) * K + skoff;
  const unsigned short* gB = BT + (size_t)(bn + srow) * K + skoff;
  unsigned short* lA = &As[(wave * 32) * 32];
  unsigned short* lB = &Bs[(wave * 32) * 32];

  const int fr = lane & 15;
  const int fq = (lane >> 4) * 8;

  for (int k0 = 0; k0 < K; k0 += 32) {
    load_lds16(gA + k0, lA);
    load_lds16(gA + k0 + 16 * K, lA + 16 * 32);
    load_lds16(gB + k0, lB);
    load_lds16(gB + k0 + 16 * K, lB + 16 * 32);
    __syncthreads();
    short8 a[4], b[4];
    #pragma unroll
    for (int i = 0; i < 4; ++i)
      a[i] = *(const short8*)&As[(wm + 16 * i + fr) * 32 + fq];
    #pragma unroll
    for (int j = 0; j < 4; ++j)
      b[j] = *(const short8*)&Bs[(wn + 16 * j + fr) * 32 + fq];
    #pragma unroll
    for (int i = 0; i < 4; ++i)
      #pragma unroll
      for (int j = 0; j < 4; ++j)
        acc[i][j] = __builtin_amdgcn_mfma_f32_16x16x32_bf16(a[i], b[j], acc[i][j], 0, 0, 0);
    __syncthreads();
  }

  // epilogue: C[row=(lane>>4)*4+r + 16i][col=(lane&15) + 16j]
  const int crow0 = bm + wm + (lane >> 4) * 4;
  const int ccol0 = bn + wn + fr;
  float bv[4];
  #pragma unroll
  for (int j = 0; j < 4; ++j) bv[j] = bias ? bias[ccol0 + 16 * j] : 0.0f;
  #pragma unroll
  for (int i = 0; i < 4; ++i) {
    #pragma unroll
    for (int r = 0; r < 4; ++r) {
      int row = crow0 + 16 * i + r;
      #pragma unroll
      for (int j = 0; j < 4; ++j) {
        int col = ccol0 + 16 * j;
        size_t idx = (size_t)row * N + col;
        float val = acc[i][j][r] + bv[j];
        if (MODE == 0) Cf[idx] = val;
        else if (MODE == 1) Cf[idx] += val;
        else if (MODE == 2) Hg[idx] = f2bf(val);
        else Hg[idx] = f2bf(bf2f(Hg[idx]) * geluf_(val));
      }
    }
  }
}

// ---------------- N=12 projection + sigmoid (mix / gates), bf16 A ----------------
__global__ __launch_bounds__(256) void proj12_kernel(
    const unsigned short* __restrict__ A, const float* __restrict__ Bw,
    const float* __restrict__ bias, float* __restrict__ out)
{
  int row = blockIdx.x * 4 + (threadIdx.x >> 6);
  int lane = threadIdx.x & 63;
  const unsigned short* ar = A + (size_t)row * DIM;
  float acc[HEADS];
  #pragma unroll
  for (int j = 0; j < HEADS; ++j) acc[j] = 0.0f;
  for (int k2 = lane; k2 < DIM; k2 += 64) {
    float a = bf2f(ar[k2]);
    const float* bw = Bw + (size_t)k2 * HEADS;
    #pragma unroll
    for (int j = 0; j < HEADS; ++j) acc[j] = fmaf(a, bw[j], acc[j]);
  }
  #pragma unroll
  for (int j = 0; j < HEADS; ++j) {
    #pragma unroll
    for (int off = 32; off; off >>= 1) acc[j] += __shfl_xor(acc[j], off);
  }
  if (lane < HEADS) {
    float r = acc[lane] + (bias ? bias[lane] : 0.0f);
    out[(size_t)row * HEADS + lane] = sigmoidf_(r);
  }
}

// ---------------- qkv postprocess: v-lerp, k-norm+gamma, rotary ----------------
__global__ __launch_bounds__(64) void qkv_fix_kernel(
    float* __restrict__ q, float* __restrict__ k, float* __restrict__ v,
    const float* __restrict__ rv, const float* __restrict__ mix,
    const float* __restrict__ kgam, int is_time)
{
  int tok = blockIdx.x; int h = blockIdx.y; int d = threadIdx.x;
  size_t idx = (size_t)tok * DIM + h * DH + d;
  float kv = k[idx];
  float ss = kv * kv;
  #pragma unroll
  for (int off = 32; off; off >>= 1) ss += __shfl_xor(ss, off);
  float nrm = fmaxf(sqrtf(ss), 1e-12f);
  kv = kv / nrm * (kgam[h * DH + d] + 1.0f) * 8.0f;   // sqrt(DH)=8
  float mv = mix[(size_t)tok * HEADS + h];
  float vv = v[idx];
  v[idx] = vv + mv * (rv[idx] - vv);
  float qv = q[idx];
  if (is_time) {
    int t = (tok >> 8) & 31;          // token = (b*32+t)*256+s
    int j = d & 31;
    float ang = (float)t * __expf(-(float)j * (9.210340371976184f / 32.0f));
    float cs = cosf(ang), sn = sinf(ang);
    float qp = __shfl_xor(qv, 32);
    float kp = __shfl_xor(kv, 32);
    float sgn = (d < 32) ? -1.0f : 1.0f;
    qv = qv * cs + sgn * qp * sn;
    kv = kv * cs + sgn * kp * sn;
  }
  q[idx] = qv;
  k[idx] = kv;
}

// ---------------- attention: data-parallel over queries, bf16 out ----------------
#define ACHUNK 128
__global__ __launch_bounds__(256) void attn_kernel(
    const float* __restrict__ q, const float* __restrict__ k,
    const float* __restrict__ v, const float* __restrict__ gate,
    unsigned short* __restrict__ o, int n, int ln, int is_time)
{
  __shared__ __align__(16) float Ks[ACHUNK][DH];
  __shared__ __align__(16) float Vs[ACHUNK][DH];
  const int tid = threadIdx.x;
  const int h = blockIdx.y;
  const int G = 256 >> ln;
  const int g = tid >> ln;
  const int qi = tid & (n - 1);
  const int bp0 = blockIdx.x * G;
  const int step = is_time ? SS : 1;

  int bp = bp0 + g;
  int base = is_time ? ((bp >> 8) * (TT * SS) + (bp & 255)) : bp * SS;
  int tq = base + qi * step;

  float4 q4[16];
  const float4* qp = (const float4*)(q + (size_t)tq * DIM + h * DH);
  #pragma unroll
  for (int c = 0; c < 16; ++c) q4[c] = qp[c];

  float4 o4[16];
  #pragma unroll
  for (int c = 0; c < 16; ++c) o4[c] = make_float4(0.f, 0.f, 0.f, 0.f);
  float sum = 0.0f;

  for (int r0 = 0; r0 < 256; r0 += ACHUNK) {
    #pragma unroll
    for (int w = 0; w < ACHUNK * (DH / 4) / 256; ++w) {
      int f = tid + w * 256;
      int r = f >> 4;
      int c4 = f & 15;
      int rr = r0 + r;
      int gg = rr >> ln;
      int jj = rr & (n - 1);
      int bpr = bp0 + gg;
      int baser = is_time ? ((bpr >> 8) * (TT * SS) + (bpr & 255)) : bpr * SS;
      int tok = baser + jj * step;
      size_t off = (size_t)tok * DIM + h * DH;
      *(float4*)&Ks[r][c4 * 4] = ((const float4*)(k + off))[c4];
      *(float4*)&Vs[r][c4 * 4] = ((const float4*)(v + off))[c4];
    }
    __syncthreads();

    int lo = max(r0, g * n);
    int hi = min(r0 + ACHUNK, (g + 1) * n);
    for (int r = lo; r < hi; ++r) {
      int j = r - g * n;
      if (is_time && j > qi) break;
      int lr = r - r0;
      const float4* kr = (const float4*)&Ks[lr][0];
      float s = 0.0f;
      #pragma unroll
      for (int c = 0; c < 16; ++c) {
        float4 kk = kr[c];
        s += q4[c].x * kk.x + q4[c].y * kk.y + q4[c].z * kk.z + q4[c].w * kk.w;
      }
      s *= 0.125f;
      s = tanhf(s * 0.02f) * 50.0f;
      float p = __expf(s);
      sum += p;
      const float4* vr = (const float4*)&Vs[lr][0];
      #pragma unroll
      for (int c = 0; c < 16; ++c) {
        float4 vv = vr[c];
        o4[c].x += p * vv.x; o4[c].y += p * vv.y;
        o4[c].z += p * vv.z; o4[c].w += p * vv.w;
      }
    }
    __syncthreads();
  }

  float gt = gate[(size_t)tq * HEADS + h] / sum;
  unsigned short* op = o + (size_t)tq * DIM + h * DH;
  #pragma unroll
  for (int c = 0; c < 16; ++c) {
    ushort4 w;
    w.x = f2bf(o4[c].x * gt); w.y = f2bf(o4[c].y * gt);
    w.z = f2bf(o4[c].z * gt); w.w = f2bf(o4[c].w * gt);
    *(ushort4*)&op[c * 4] = w;
  }
}

// ---------------- driver ----------------
extern "C" void kernel_launch(void* const* d_in, const int* in_sizes, int n_in,
                              void* d_out, int out_size, void* d_ws, size_t ws_size,
                              hipStream_t stream)
{
  const float* tokens = (const float*)d_in[0];
  const float* attn_norm_w = (const float*)d_in[1];
  const float* Wq   = (const float*)d_in[2];
  const float* Wk   = (const float*)d_in[3];
  const float* Wv   = (const float*)d_in[4];
  const float* Wo   = (const float*)d_in[5];
  const float* Wg   = (const float*)d_in[6];
  const float* Wmix = (const float*)d_in[7];
  const float* bmix = (const float*)d_in[8];
  const float* kgam = (const float*)d_in[9];
  const float* ffw  = (const float*)d_in[10];
  const float* Win  = (const float*)d_in[11];
  const float* bin  = (const float*)d_in[12];
  const float* Wout = (const float*)d_in[13];
  const float* bout = (const float*)d_in[14];
  const float* vrw  = (const float*)d_in[15];
  const float* vrW  = (const float*)d_in[16];
  const float* fnw  = (const float*)d_in[17];

  const size_t NT = (size_t)NTOK * DIM;   // 12,582,912
  float* ws  = (float*)d_ws;
  float* x   = ws;                        // NT f32
  float* q   = x  + NT;                   // NT f32
  float* k   = q  + NT;                   // NT f32
  float* v   = k  + NT;                   // NT f32
  float* rv  = v  + NT;                   // NT f32
  float* mix = rv + NT;                   // NTOK*12
  float* gate = mix + (size_t)NTOK * HEADS;
  unsigned short* tn   = (unsigned short*)(gate + (size_t)NTOK * HEADS); // NT bf16
  unsigned short* wqT  = tn + NT;                    // per-layer bf16 weights
  unsigned short* wkT  = wqT + 768 * 768;
  unsigned short* wvT  = wkT + 768 * 768;
  unsigned short* woT  = wvT + 768 * 768;
  unsigned short* winT = woT + 768 * 768;            // 4096*768
  unsigned short* woutT= winT + (size_t)4096 * 768;  // 768*2048
  unsigned short* vrWT = woutT + (size_t)768 * 2048; // 768*768
  unsigned short* hg   = (unsigned short*)q;         // 16384*2048 bf16, aliases q+k

  hipMemcpyAsync(x, tokens, NT * sizeof(float), hipMemcpyDeviceToDevice, stream);

  // value residual: rv = rmsnorm(tokens, vrw) @ vrW
  w_to_bt<<<dim3(24, 24), 256, 0, stream>>>(vrW, vrWT, DIM, DIM);
  rmsnorm_kernel<1><<<NTOK, 256, 0, stream>>>(tokens, vrw, tn);
  gemm_bf16<0><<<dim3(6, 128), 256, 0, stream>>>(
      tn, vrWT, rv, nullptr, nullptr, NTOK, DIM, DIM);

  for (int i = 0; i < DEPTH; ++i) {
    int is_time = ((i + 1) % 4 == 0) ? 1 : 0;
    // per-layer weight conversion (bf16, transposed)
    w_to_bt<<<dim3(24, 24), 256, 0, stream>>>(Wq + (size_t)i * DIM * DIM, wqT, DIM, DIM);
    w_to_bt<<<dim3(24, 24), 256, 0, stream>>>(Wk + (size_t)i * DIM * DIM, wkT, DIM, DIM);
    w_to_bt<<<dim3(24, 24), 256, 0, stream>>>(Wv + (size_t)i * DIM * DIM, wvT, DIM, DIM);
    w_to_bt<<<dim3(24, 24), 256, 0, stream>>>(Wo + (size_t)i * DIM * DIM, woT, DIM, DIM);
    w_to_bt<<<dim3(128, 24), 256, 0, stream>>>(Win + (size_t)i * DIM * 2 * DFF, winT, DIM, 2 * DFF);
    w_to_bt<<<dim3(24, 64), 256, 0, stream>>>(Wout + (size_t)i * DFF * DIM, woutT, DFF, DIM);

    rmsnorm_kernel<1><<<NTOK, 256, 0, stream>>>(x, attn_norm_w + (size_t)i * DIM, tn);
    gemm_bf16<0><<<dim3(6, 128), 256, 0, stream>>>(tn, wqT, q, nullptr, nullptr, NTOK, DIM, DIM);
    gemm_bf16<0><<<dim3(6, 128), 256, 0, stream>>>(tn, wkT, k, nullptr, nullptr, NTOK, DIM, DIM);
    gemm_bf16<0><<<dim3(6, 128), 256, 0, stream>>>(tn, wvT, v, nullptr, nullptr, NTOK, DIM, DIM);
    proj12_kernel<<<NTOK / 4, 256, 0, stream>>>(
        tn, Wmix + (size_t)i * DIM * HEADS, bmix + (size_t)i * HEADS, mix);
    proj12_kernel<<<NTOK / 4, 256, 0, stream>>>(
        tn, Wg + (size_t)i * DIM * HEADS, nullptr, gate);
    qkv_fix_kernel<<<dim3(NTOK, HEADS), 64, 0, stream>>>(
        q, k, v, rv, mix, kgam + (size_t)i * HEADS * DH, is_time);
    if (is_time)
      attn_kernel<<<dim3((BB * SS) / 8, HEADS), 256, 0, stream>>>(
          q, k, v, gate, tn, TT, 5, 1);
    else
      attn_kernel<<<dim3(BB * TT, HEADS), 256, 0, stream>>>(
          q, k, v, gate, tn, SS, 8, 0);
    gemm_bf16<1><<<dim3(6, 128), 256, 0, stream>>>(tn, woT, x, nullptr, nullptr, NTOK, DIM, DIM);
    // FF
    rmsnorm_kernel<1><<<NTOK, 256, 0, stream>>>(x, ffw + (size_t)i * DIM, tn);
    gemm_bf16<2><<<dim3(16, 128), 256, 0, stream>>>(
        tn, winT, nullptr, hg, bin + (size_t)i * 2 * DFF, NTOK, DFF, DIM);
    gemm_bf16<3><<<dim3(16, 128), 256, 0, stream>>>(
        tn, winT + (size_t)DFF * DIM, nullptr, hg, bin + (size_t)i * 2 * DFF + DFF,
        NTOK, DFF, DIM);
    gemm_bf16<1><<<dim3(6, 128), 256, 0, stream>>>(
        hg, woutT, x, nullptr, bout + (size_t)i * DIM, NTOK, DIM, DFF);
  }
  rmsnorm_kernel<0><<<NTOK, 256, 0, stream>>>(x, fnw, (float*)d_out);
}